// Round 1
// baseline (656.097 us; speedup 1.0000x reference)
//
#include <hip/hip_runtime.h>

// SelfAttention: B=4, L=4096, H=256, fp32 in/out.
// Round 10: TLP for the attn kernel. Counters showed MfmaUtil 19.6 / VALUBusy
// 29.8 / HBM 5% / Occupancy 20% -> latency/sync-bound at 2 blocks/CU (grid
// 512). Changes: split-K 2 -> 4 (grid 1024 = exactly 4 blocks/CU); P LDS
// scratch shrunk from 64-key stride-72 (9216 B) to a REUSED 32-key stride-40
// half-buffer (5120 B) so LDS = 37888 <= 40960 -> 4 resident blocks/CU
// (launch_bounds (256,4), VGPR 112 < 128 cap). P round-trip now two 32-key
// halves; wave-local DS pipe is in-order so the half-B overwrite needs no
// barrier. s_setprio(1) wraps QK/PV MFMA clusters (4 independent blocks/CU
// now give the scheduler role diversity to arbitrate). 4-way merge.
// Carried from r9: all-fp16 attention core, DMA-dbuf K staging, DPP softmax,
// alpha-skip, uniform bases, 64-key macro softmax.

typedef __bf16 bf16x8 __attribute__((ext_vector_type(8)));
typedef _Float16 f16x8 __attribute__((ext_vector_type(8)));
typedef _Float16 f16x4 __attribute__((ext_vector_type(4)));
typedef float floatx4 __attribute__((ext_vector_type(4)));

#define MFMA16B(a, b, c) __builtin_amdgcn_mfma_f32_16x16x32_bf16(a, b, c, 0, 0, 0)
#define MFMA16F(a, b, c) __builtin_amdgcn_mfma_f32_16x16x32_f16(a, b, c, 0, 0, 0)
#define GLOAD_LDS16(g, l)                                                  \
  __builtin_amdgcn_global_load_lds(                                        \
      (const __attribute__((address_space(1))) void *)(g),                 \
      (__attribute__((address_space(3))) void *)(l), 16, 0, 0)

#define HID 256
#define LSEQ 4096
#define NB 4
#define NTOK (NB * LSEQ)             // 16384
#define PLANE ((size_t)NTOK * HID)   // 4,194,304 elements
#define NSPLIT 4                     // split-K over key range
#define QSCALE 0.09016844005556021f  // log2(e)/16 ; softmax uses exp2

// Layouts:
//  Wht/Wlt [3][n][h] row-major hi/lo bf16 weights (transposed).
//  Qf [tok][h] row-major fp16 (pre-scaled by QSCALE).
//  Kf (32-key tiles, T = tok>>5, 512 tiles): [T][nt(2)][kc(8)][lane(64)][j(8)]
//    fp16, tile stride 8192 el (16 KB).
//    element = K[key = T*32 + nt*16 + (lane&15)][h = kc*32 + (lane>>4)*8 + j]
//  Vf (32-key tiles): [T][dt(16)][lane][j] fp16, tile stride 8192 el.
//    element = V[key = T*32 + (lane>>4)*8 + j][d = dt*16 + (lane&15)]

__device__ __forceinline__ void split_bf16(float v, __bf16 &h, __bf16 &l) {
  h = (__bf16)v;
  l = (__bf16)(v - (float)h);
}

// DPP 16-lane-row butterfly reductions (VALU, no LDS pipe).
template <int N>
__device__ __forceinline__ float dpp_ror(float v) {
  return __builtin_bit_cast(float,
      __builtin_amdgcn_update_dpp(0, __builtin_bit_cast(int, v),
                                  0x120 + N, 0xf, 0xf, true));
}
__device__ __forceinline__ float row_sum16(float v) {
  v += dpp_ror<1>(v);
  v += dpp_ror<2>(v);
  v += dpp_ror<4>(v);
  v += dpp_ror<8>(v);
  return v;
}
__device__ __forceinline__ float row_max16(float v) {
  v = fmaxf(v, dpp_ror<1>(v));
  v = fmaxf(v, dpp_ror<2>(v));
  v = fmaxf(v, dpp_ror<4>(v));
  v = fmaxf(v, dpp_ror<8>(v));
  return v;
}

// ---------------------------------------------------------------------------
// Kernel 1: transpose + hi/lo-split weights -> Wht/Wlt [3][n][h] row-major.
// grid (3, 8): one 32-h-row slab per block.
// ---------------------------------------------------------------------------
__global__ __launch_bounds__(256) void wsplit(const float *__restrict__ Wq,
                                              const float *__restrict__ Wk,
                                              const float *__restrict__ Wv,
                                              __bf16 *__restrict__ Wht,
                                              __bf16 *__restrict__ Wlt) {
  __shared__ float tile[32][256];
  const int wsel = blockIdx.x;
  const int hb = blockIdx.y;
  const float *W = (wsel == 0) ? Wq : (wsel == 1) ? Wk : Wv;
  __bf16 *oh = Wht + wsel * HID * HID;
  __bf16 *ol = Wlt + wsel * HID * HID;
  const int t = threadIdx.x;
  #pragma unroll
  for (int p = 0; p < 8; ++p) {
    int r = p * 4 + (t >> 6);
    int c = (t & 63) * 4;
    *(floatx4 *)&tile[r][c] = *(const floatx4 *)&W[(hb * 32 + r) * HID + c];
  }
  __syncthreads();
  #pragma unroll
  for (int q = 0; q < 4; ++q) {
    int n = q * 64 + (t >> 2);
    int hs = (t & 3) * 8;
    bf16x8 hh, ll;
    #pragma unroll
    for (int i = 0; i < 8; ++i) {
      float v = tile[hs + i][n];
      __bf16 h, l;
      split_bf16(v, h, l);
      hh[i] = h; ll[i] = l;
    }
    *(bf16x8 *)&oh[n * HID + hb * 32 + hs] = hh;
    *(bf16x8 *)&ol[n * HID + hb * 32 + hs] = ll;
  }
}

// ---------------------------------------------------------------------------
// Kernel 2: QKV projection (3-product split-bf16 GEMM, unchanged math).
// W tiles staged in LDS (xor-swizzle) with next-phase reg-prefetch. Epilogues
// emit SINGLE fp16 planes: Q row-major (scaled), K/V fragment-linear via
// one LDS scratch transpose. grid = (256 m-tiles, 4 col-tiles), 2 blocks/CU.
// ---------------------------------------------------------------------------
__global__ __launch_bounds__(256, 2) void qkv_proj(const float *__restrict__ X,
                                                   const __bf16 *__restrict__ Wht,
                                                   const __bf16 *__restrict__ Wlt,
                                                   _Float16 *__restrict__ Qf,
                                                   _Float16 *__restrict__ Kf,
                                                   _Float16 *__restrict__ Vf) {
  __shared__ __bf16 WhS[64 * 256];
  __shared__ __bf16 WlS[64 * 256];
  _Float16 *Tf = (_Float16 *)WhS;  // 64 x 72 fp16 scratch (aliases WhS)

  const int mtile = blockIdx.x;
  const int col0 = blockIdx.y * 64;
  const int tid = threadIdx.x;
  const int w4 = tid >> 6;
  const int lane = tid & 63;
  const int quad = lane >> 4;
  const int ln = lane & 15;
  const int arow = mtile * 64 + w4 * 16 + ln;

  bf16x8 ah[8], al[8];
  #pragma unroll
  for (int kc = 0; kc < 8; ++kc) {
    const float *xp = X + (size_t)arow * HID + kc * 32 + quad * 8;
    floatx4 x0 = *(const floatx4 *)xp;
    floatx4 x1 = *(const floatx4 *)(xp + 4);
    #pragma unroll
    for (int j = 0; j < 4; ++j) {
      __bf16 h, l;
      split_bf16(x0[j], h, l); ah[kc][j] = h; al[kc][j] = l;
      split_bf16(x1[j], h, l); ah[kc][4 + j] = h; al[kc][4 + j] = l;
    }
  }

  const int srow = tid >> 2;
  const int sseg = tid & 3;

  bf16x8 pwh[8], pwl[8];
  {
    const size_t wbase = (size_t)(col0 + srow) * HID;
    #pragma unroll
    for (int j = 0; j < 8; ++j) {
      const int chunk = j * 4 + sseg;
      pwh[j] = *(const bf16x8 *)&Wht[wbase + chunk * 8];
      pwl[j] = *(const bf16x8 *)&Wlt[wbase + chunk * 8];
    }
  }

  for (int w = 0; w < 3; ++w) {
    __syncthreads();  // W region free (prev MFMA reads / scratch reads done)
    #pragma unroll
    for (int j = 0; j < 8; ++j) {
      const int chunk = j * 4 + sseg;
      const int dst = srow * 256 + ((chunk ^ (srow & 7)) << 3);
      *(bf16x8 *)&WhS[dst] = pwh[j];
      *(bf16x8 *)&WlS[dst] = pwl[j];
    }
    __syncthreads();

    if (w < 2) {
      const size_t wbase = (size_t)(w + 1) * HID * HID + (size_t)(col0 + srow) * HID;
      #pragma unroll
      for (int j = 0; j < 8; ++j) {
        const int chunk = j * 4 + sseg;
        pwh[j] = *(const bf16x8 *)&Wht[wbase + chunk * 8];
        pwl[j] = *(const bf16x8 *)&Wlt[wbase + chunk * 8];
      }
    }

    floatx4 acc[4] = {};
    #pragma unroll
    for (int kc = 0; kc < 8; ++kc) {
      #pragma unroll
      for (int nt = 0; nt < 4; ++nt) {
        const int a = (nt * 16 + ln) * 256 + (((kc * 4 + quad) ^ (ln & 7)) << 3);
        bf16x8 bh = *(const bf16x8 *)&WhS[a];
        bf16x8 bl = *(const bf16x8 *)&WlS[a];
        acc[nt] = MFMA16B(ah[kc], bh, acc[nt]);
        acc[nt] = MFMA16B(ah[kc], bl, acc[nt]);
        acc[nt] = MFMA16B(al[kc], bh, acc[nt]);
      }
    }

    // Epilogues. C/D layout: col = lane&15, row = quad*4 + reg.
    if (w == 0) {
      #pragma unroll
      for (int nt = 0; nt < 4; ++nt) {
        #pragma unroll
        for (int r = 0; r < 4; ++r) {
          const int orow = mtile * 64 + w4 * 16 + quad * 4 + r;
          const int ocol = col0 + nt * 16 + ln;
          Qf[(size_t)orow * HID + ocol] = (_Float16)(acc[nt][r] * QSCALE);
        }
      }
    } else if (w == 1) {
      __syncthreads();  // all MFMA reads of WhS done before scratch clobber
      #pragma unroll
      for (int nt = 0; nt < 4; ++nt) {
        #pragma unroll
        for (int r = 0; r < 4; ++r) {
          const int tok_l = w4 * 16 + quad * 4 + r;
          const int h_l = nt * 16 + ln;
          Tf[tok_l * 72 + h_l] = (_Float16)acc[nt][r];
        }
      }
      __syncthreads();
      #pragma unroll
      for (int i = 0; i < 2; ++i) {     // 512 chunks of 16B
        const int c = i * 256 + tid;
        const int lane_f = c & 63;
        const int ntf = (c >> 6) & 1;
        const int kcL = (c >> 7) & 1;
        const int t2 = (c >> 8) & 1;
        const int qf = lane_f >> 4;
        const int lnf = lane_f & 15;
        const int tok_l = t2 * 32 + ntf * 16 + lnf;
        f16x8 v = *(const f16x8 *)&Tf[tok_l * 72 + kcL * 32 + qf * 8];
        const int T = mtile * 2 + t2;
        const int kc = (col0 >> 5) + kcL;
        *(f16x8 *)&Kf[(size_t)T * 8192 + ((ntf * 8 + kc) * 64 + lane_f) * 8] = v;
      }
    } else {
      __syncthreads();
      #pragma unroll
      for (int nt = 0; nt < 4; ++nt) {
        #pragma unroll
        for (int r = 0; r < 4; ++r) {
          const int tok_l = w4 * 16 + quad * 4 + r;
          const int d_l = nt * 16 + ln;
          Tf[d_l * 72 + tok_l] = (_Float16)acc[nt][r];
        }
      }
      __syncthreads();
      #pragma unroll
      for (int i = 0; i < 2; ++i) {     // 512 chunks of 16B
        const int c = i * 256 + tid;
        const int lane_f = c & 63;
        const int dtL = (c >> 6) & 3;
        const int t2 = (c >> 8) & 1;
        const int qf = lane_f >> 4;
        const int lnf = lane_f & 15;
        const int d_l = dtL * 16 + lnf;
        f16x8 v = *(const f16x8 *)&Tf[d_l * 72 + t2 * 32 + qf * 8];
        const int T = mtile * 2 + t2;
        const int dt = (col0 >> 4) + dtL;
        *(f16x8 *)&Vf[(size_t)(T * 16 + dt) * 512 + lane_f * 8] = v;
      }
    }
  }
}

// ---------------------------------------------------------------------------
// Kernel 3: flash attention, all-fp16 operands. grid = 1024 (qt=bx>>2,
// ks=bx&3), 256 thr, 4 blocks/CU (LDS 37888 B: KS0+KS1 32 KB + 5 KB P
// scratch). Per 64-key macro: DMA-dbuf KS0/KS1 (16 KB tiles, one barrier
// each), single-product fp16 QK (2-way kc-split chains), ONE softmax, P
// round-trip in two 32-key halves through a reused per-wave scratch (DS pipe
// is in-order within a wave -> no barrier for the overwrite). V direct from
// global; DPP reductions; alpha-skip; setprio around MFMA clusters.
// ---------------------------------------------------------------------------
__global__ __launch_bounds__(256, 4) void attn(const _Float16 *__restrict__ Qf,
                                               const _Float16 *__restrict__ Kf,
                                               const _Float16 *__restrict__ Vf,
                                               _Float16 *__restrict__ Op,
                                               float *__restrict__ Mp,
                                               float *__restrict__ Lp) {
  __shared__ _Float16 KS0[8192];
  __shared__ _Float16 KS1[8192];
  __shared__ _Float16 PsS[4 * 16 * 40];  // per-wave 16 x 40 (32 keys + pad)

  const int bx = blockIdx.x;
  const int ks = bx & 3;
  const int qt = bx >> 2;
  const int b = qt >> 6;
  const int qtl = qt & 63;
  const int tid = threadIdx.x;
  const int w4 = tid >> 6;
  const int lane = tid & 63;
  const int quad = lane >> 4;
  const int ln = lane & 15;
  const int T0 = b * 128 + ks * 32;  // 32 key-tiles (1024 keys) per block

  const int qtok = b * LSEQ + qtl * 64 + w4 * 16 + ln;
  f16x8 q[8];
  #pragma unroll
  for (int kc = 0; kc < 8; ++kc)
    q[kc] = *(const f16x8 *)&Qf[(size_t)qtok * HID + kc * 32 + quad * 8];

  // Uniform bases (SALU) + fixed per-lane offsets.
  const _Float16 *kuni = Kf + (size_t)T0 * 8192;
  const _Float16 *vuni = Vf + (size_t)T0 * 8192;
  const int koff = tid * 8;
  const int voff = lane * 8;

  // Prologue: DMA tile 0 -> KS0 (4 rounds x 4 KB).
  #pragma unroll
  for (int i = 0; i < 4; ++i)
    GLOAD_LDS16(kuni + i * 2048 + koff, &KS0[i * 2048 + koff]);

  float m[4] = {-1e30f, -1e30f, -1e30f, -1e30f};
  float l[4] = {0.f, 0.f, 0.f, 0.f};
  floatx4 o[16] = {};

  for (int jm = 0; jm < 16; ++jm) {
    floatx4 s[4];
    // ---------- tile A (keys 64*jm..+31) from KS0 ----------
    __syncthreads();  // drains KS0's DMA; all waves done reading KS1 (prev macro)
    {
      const _Float16 *src = kuni + (size_t)(2 * jm + 1) * 8192 + koff;
      #pragma unroll
      for (int i = 0; i < 4; ++i)
        GLOAD_LDS16(src + i * 2048, &KS1[i * 2048 + koff]);
    }
    {
      floatx4 pa[2] = {}, pb[2] = {};
      __builtin_amdgcn_s_setprio(1);
      #pragma unroll
      for (int nt = 0; nt < 2; ++nt)
        #pragma unroll
        for (int kc = 0; kc < 4; ++kc) {
          pa[nt] = MFMA16F(q[kc], *(const f16x8 *)(KS0 + (nt * 8 + kc) * 512 + voff), pa[nt]);
          pb[nt] = MFMA16F(q[4 + kc], *(const f16x8 *)(KS0 + (nt * 8 + 4 + kc) * 512 + voff), pb[nt]);
        }
      __builtin_amdgcn_s_setprio(0);
      s[0] = pa[0] + pb[0];
      s[1] = pa[1] + pb[1];
    }
    // ---------- tile B (keys +32..+63) from KS1 ----------
    __syncthreads();  // drains KS1's DMA; all waves done reading KS0
    if (jm < 15) {
      const _Float16 *src = kuni + (size_t)(2 * jm + 2) * 8192 + koff;
      #pragma unroll
      for (int i = 0; i < 4; ++i)
        GLOAD_LDS16(src + i * 2048, &KS0[i * 2048 + koff]);
    }
    const _Float16 *va = vuni + (size_t)(2 * jm) * 8192;
    const _Float16 *vbp = vuni + (size_t)(2 * jm + 1) * 8192;
    f16x8 vb0[8];
    #pragma unroll
    for (int dt = 0; dt < 8; ++dt)
      vb0[dt] = *(const f16x8 *)(va + dt * 512 + voff);
    {
      floatx4 pa[2] = {}, pb[2] = {};
      __builtin_amdgcn_s_setprio(1);
      #pragma unroll
      for (int nt = 0; nt < 2; ++nt)
        #pragma unroll
        for (int kc = 0; kc < 4; ++kc) {
          pa[nt] = MFMA16F(q[kc], *(const f16x8 *)(KS1 + (nt * 8 + kc) * 512 + voff), pa[nt]);
          pb[nt] = MFMA16F(q[4 + kc], *(const f16x8 *)(KS1 + (nt * 8 + 4 + kc) * 512 + voff), pb[nt]);
        }
      __builtin_amdgcn_s_setprio(0);
      s[2] = pa[0] + pb[0];
      s[3] = pa[1] + pb[1];
    }
    f16x8 vb1[8];
    #pragma unroll
    for (int dt = 0; dt < 8; ++dt)
      vb1[dt] = *(const f16x8 *)(va + (8 + dt) * 512 + voff);

    // ---------- softmax over 64 keys (base-2, DPP) ----------
    float alpha[4];
    #pragma unroll
    for (int r = 0; r < 4; ++r) {
      const float tmax = row_max16(
          fmaxf(fmaxf(s[0][r], s[1][r]), fmaxf(s[2][r], s[3][r])));
      const float mn = fmaxf(m[r], tmax);
      const float al = exp2f(m[r] - mn);
      const float p0 = exp2f(s[0][r] - mn);
      const float p1 = exp2f(s[1][r] - mn);
      const float p2 = exp2f(s[2][r] - mn);
      const float p3 = exp2f(s[3][r] - mn);
      s[0][r] = p0; s[1][r] = p1; s[2][r] = p2; s[3][r] = p3;
      const float rs = row_sum16((p0 + p1) + (p2 + p3));
      l[r] = l[r] * al + rs;
      m[r] = mn;
      alpha[r] = al;
    }

    // ---------- P half A (keys 0..31) write: C-layout -> A-layout ----------
    _Float16 *ps = PsS + w4 * (16 * 40);
    #pragma unroll
    for (int nt = 0; nt < 2; ++nt)
      #pragma unroll
      for (int r = 0; r < 4; ++r)
        ps[(quad * 4 + r) * 40 + nt * 16 + ln] = (_Float16)s[nt][r];

    // ---------- O rescale (alpha-skip; near-one-hot -> mostly skipped) ------
    const float amin = fminf(fminf(alpha[0], alpha[1]), fminf(alpha[2], alpha[3]));
    if (__any(amin < 1.0f)) {
      #pragma unroll
      for (int dt = 0; dt < 16; ++dt) {
        o[dt][0] *= alpha[0]; o[dt][1] *= alpha[1];
        o[dt][2] *= alpha[2]; o[dt][3] *= alpha[3];
      }
    }

    const f16x8 paA = *(const f16x8 *)&ps[ln * 40 + quad * 8];

    // ---------- O += P V, keys 0..31 ----------
    __builtin_amdgcn_s_setprio(1);
    #pragma unroll
    for (int dt = 0; dt < 8; ++dt) o[dt] = MFMA16F(paA, vb0[dt], o[dt]);
    __builtin_amdgcn_s_setprio(0);
    f16x8 vb2[8];
    #pragma unroll
    for (int dt = 0; dt < 8; ++dt)
      vb2[dt] = *(const f16x8 *)(vbp + dt * 512 + voff);
    __builtin_amdgcn_s_setprio(1);
    #pragma unroll
    for (int dt = 0; dt < 8; ++dt) o[8 + dt] = MFMA16F(paA, vb1[dt], o[8 + dt]);
    __builtin_amdgcn_s_setprio(0);
    f16x8 vb3[8];
    #pragma unroll
    for (int dt = 0; dt < 8; ++dt)
      vb3[dt] = *(const f16x8 *)(vbp + (8 + dt) * 512 + voff);

    // ---------- P half B (keys 32..63): reuse scratch (DS in-order) --------
    #pragma unroll
    for (int nt = 0; nt < 2; ++nt)
      #pragma unroll
      for (int r = 0; r < 4; ++r)
        ps[(quad * 4 + r) * 40 + nt * 16 + ln] = (_Float16)s[2 + nt][r];

    const f16x8 paB = *(const f16x8 *)&ps[ln * 40 + quad * 8];

    // ---------- O += P V, keys 32..63 ----------
    __builtin_amdgcn_s_setprio(1);
    #pragma unroll
    for (int dt = 0; dt < 8; ++dt) o[dt] = MFMA16F(paB, vb2[dt], o[dt]);
    #pragma unroll
    for (int dt = 0; dt < 8; ++dt) o[8 + dt] = MFMA16F(paB, vb3[dt], o[8 + dt]);
    __builtin_amdgcn_s_setprio(0);
  }

  const int rowbase = b * LSEQ + qtl * 64 + w4 * 16 + quad * 4;
  #pragma unroll
  for (int dt = 0; dt < 16; ++dt)
    #pragma unroll
    for (int r = 0; r < 4; ++r)
      Op[(size_t)ks * PLANE + (size_t)(rowbase + r) * HID + dt * 16 + ln] =
          (_Float16)o[dt][r];
  if (ln == 0) {
    #pragma unroll
    for (int r = 0; r < 4; ++r) {
      Mp[ks * NTOK + rowbase + r] = m[r];
      Lp[ks * NTOK + rowbase + r] = l[r];
    }
  }
}

// ---------------------------------------------------------------------------
// Kernel 4: split-K merge, 4-way (fp16 partials).
// ---------------------------------------------------------------------------
__global__ __launch_bounds__(256) void merge(const _Float16 *__restrict__ Op,
                                             const float *__restrict__ Mp,
                                             const float *__restrict__ Lp,
                                             float *__restrict__ Out) {
  const int row = blockIdx.x * 4 + (threadIdx.x >> 6);
  const int c = (threadIdx.x & 63) * 4;
  float ms[NSPLIT], ls[NSPLIT];
  #pragma unroll
  for (int s = 0; s < NSPLIT; ++s) {
    ms[s] = Mp[s * NTOK + row];
    ls[s] = Lp[s * NTOK + row];
  }
  const float M = fmaxf(fmaxf(ms[0], ms[1]), fmaxf(ms[2], ms[3]));
  float e[NSPLIT], den = 0.f;
  #pragma unroll
  for (int s = 0; s < NSPLIT; ++s) {
    e[s] = exp2f(ms[s] - M);
    den += ls[s] * e[s];
  }
  const float inv = 1.0f / den;
  floatx4 out = {};
  #pragma unroll
  for (int s = 0; s < NSPLIT; ++s) {
    const f16x4 a = *(const f16x4 *)&Op[(size_t)s * PLANE + (size_t)row * HID + c];
    const float w = e[s] * inv;
    #pragma unroll
    for (int i = 0; i < 4; ++i) out[i] += w * (float)a[i];
  }
  *(floatx4 *)&Out[(size_t)row * HID + c] = out;
}

// ---------------------------------------------------------------------------
extern "C" void kernel_launch(void *const *d_in, const int *in_sizes, int n_in,
                              void *d_out, int out_size, void *d_ws, size_t ws_size,
                              hipStream_t stream) {
  const float *X = (const float *)d_in[0];
  const float *Wq = (const float *)d_in[1];
  const float *Wk = (const float *)d_in[2];
  const float *Wv = (const float *)d_in[3];
  // d_in[4] = lengths (unused by reference)

  // Workspace (2-byte elements). ~60 MB total.
  _Float16 *ws = (_Float16 *)d_ws;
  _Float16 *Qf = ws;                          // [16384][256] row-major fp16
  _Float16 *Kf = Qf + PLANE;                  // 32-key frag-linear fp16
  _Float16 *Vf = Kf + PLANE;                  // 32-key frag-linear fp16
  __bf16 *Wht = (__bf16 *)(Vf + PLANE);       // [3][256][256] bf16 hi
  __bf16 *Wlt = Wht + 3 * HID * HID;          // bf16 lo
  _Float16 *Op = (_Float16 *)(Wlt + 3 * HID * HID);  // [4][16384][256] fp16
  float *Mp = (float *)(Op + NSPLIT * PLANE); // [4][16384]
  float *Lp = Mp + NSPLIT * NTOK;             // [4][16384]

  wsplit<<<dim3(3, 8), 256, 0, stream>>>(Wq, Wk, Wv, Wht, Wlt);
  qkv_proj<<<dim3(256, 4), 256, 0, stream>>>(X, Wht, Wlt, Qf, Kf, Vf);
  attn<<<NTOK / 64 * NSPLIT, 256, 0, stream>>>(Qf, Kf, Vf, Op, Mp, Lp);
  merge<<<NTOK / 4, 256, 0, stream>>>(Op, Mp, Lp, (float *)d_out);
}

// Round 2
// 220.326 us; speedup vs baseline: 2.9778x; 2.9778x over previous
//
#include <hip/hip_runtime.h>

// SelfAttention: B=4, L=4096, H=256, fp32 in/out.
// Round 11: fix round-10 spill catastrophe. (256,4) launch_bounds capped the
// attn kernel at 128 VGPRs -> accumulator spill to scratch (VGPR 64, 2.6 GB
// of HBM spill traffic, 570 us). Revert to (256,2): compiler uses ~112 VGPR,
// and the HARDWARE occupancy limit is then min(512/112 -> 4 waves/SIMD,
// LDS 37888 B -> 4 blocks/CU) = 4 blocks/CU WITHOUT any register cap.
// Keep from r10: split-K 4 (grid 1024 = 4 blocks/CU), 32-key stride-40 reused
// P scratch (LDS 37888), setprio on MFMA clusters, 4-way merge.
// Carried from r9: all-fp16 attention core, DMA-dbuf K staging, DPP softmax,
// alpha-skip, uniform bases, 64-key macro softmax.

typedef __bf16 bf16x8 __attribute__((ext_vector_type(8)));
typedef _Float16 f16x8 __attribute__((ext_vector_type(8)));
typedef _Float16 f16x4 __attribute__((ext_vector_type(4)));
typedef float floatx4 __attribute__((ext_vector_type(4)));

#define MFMA16B(a, b, c) __builtin_amdgcn_mfma_f32_16x16x32_bf16(a, b, c, 0, 0, 0)
#define MFMA16F(a, b, c) __builtin_amdgcn_mfma_f32_16x16x32_f16(a, b, c, 0, 0, 0)
#define GLOAD_LDS16(g, l)                                                  \
  __builtin_amdgcn_global_load_lds(                                        \
      (const __attribute__((address_space(1))) void *)(g),                 \
      (__attribute__((address_space(3))) void *)(l), 16, 0, 0)

#define HID 256
#define LSEQ 4096
#define NB 4
#define NTOK (NB * LSEQ)             // 16384
#define PLANE ((size_t)NTOK * HID)   // 4,194,304 elements
#define NSPLIT 4                     // split-K over key range
#define QSCALE 0.09016844005556021f  // log2(e)/16 ; softmax uses exp2

// Layouts:
//  Wht/Wlt [3][n][h] row-major hi/lo bf16 weights (transposed).
//  Qf [tok][h] row-major fp16 (pre-scaled by QSCALE).
//  Kf (32-key tiles, T = tok>>5, 512 tiles): [T][nt(2)][kc(8)][lane(64)][j(8)]
//    fp16, tile stride 8192 el (16 KB).
//    element = K[key = T*32 + nt*16 + (lane&15)][h = kc*32 + (lane>>4)*8 + j]
//  Vf (32-key tiles): [T][dt(16)][lane][j] fp16, tile stride 8192 el.
//    element = V[key = T*32 + (lane>>4)*8 + j][d = dt*16 + (lane&15)]

__device__ __forceinline__ void split_bf16(float v, __bf16 &h, __bf16 &l) {
  h = (__bf16)v;
  l = (__bf16)(v - (float)h);
}

// DPP 16-lane-row butterfly reductions (VALU, no LDS pipe).
template <int N>
__device__ __forceinline__ float dpp_ror(float v) {
  return __builtin_bit_cast(float,
      __builtin_amdgcn_update_dpp(0, __builtin_bit_cast(int, v),
                                  0x120 + N, 0xf, 0xf, true));
}
__device__ __forceinline__ float row_sum16(float v) {
  v += dpp_ror<1>(v);
  v += dpp_ror<2>(v);
  v += dpp_ror<4>(v);
  v += dpp_ror<8>(v);
  return v;
}
__device__ __forceinline__ float row_max16(float v) {
  v = fmaxf(v, dpp_ror<1>(v));
  v = fmaxf(v, dpp_ror<2>(v));
  v = fmaxf(v, dpp_ror<4>(v));
  v = fmaxf(v, dpp_ror<8>(v));
  return v;
}

// ---------------------------------------------------------------------------
// Kernel 1: transpose + hi/lo-split weights -> Wht/Wlt [3][n][h] row-major.
// grid (3, 8): one 32-h-row slab per block.
// ---------------------------------------------------------------------------
__global__ __launch_bounds__(256) void wsplit(const float *__restrict__ Wq,
                                              const float *__restrict__ Wk,
                                              const float *__restrict__ Wv,
                                              __bf16 *__restrict__ Wht,
                                              __bf16 *__restrict__ Wlt) {
  __shared__ float tile[32][256];
  const int wsel = blockIdx.x;
  const int hb = blockIdx.y;
  const float *W = (wsel == 0) ? Wq : (wsel == 1) ? Wk : Wv;
  __bf16 *oh = Wht + wsel * HID * HID;
  __bf16 *ol = Wlt + wsel * HID * HID;
  const int t = threadIdx.x;
  #pragma unroll
  for (int p = 0; p < 8; ++p) {
    int r = p * 4 + (t >> 6);
    int c = (t & 63) * 4;
    *(floatx4 *)&tile[r][c] = *(const floatx4 *)&W[(hb * 32 + r) * HID + c];
  }
  __syncthreads();
  #pragma unroll
  for (int q = 0; q < 4; ++q) {
    int n = q * 64 + (t >> 2);
    int hs = (t & 3) * 8;
    bf16x8 hh, ll;
    #pragma unroll
    for (int i = 0; i < 8; ++i) {
      float v = tile[hs + i][n];
      __bf16 h, l;
      split_bf16(v, h, l);
      hh[i] = h; ll[i] = l;
    }
    *(bf16x8 *)&oh[n * HID + hb * 32 + hs] = hh;
    *(bf16x8 *)&ol[n * HID + hb * 32 + hs] = ll;
  }
}

// ---------------------------------------------------------------------------
// Kernel 2: QKV projection (3-product split-bf16 GEMM, unchanged math).
// W tiles staged in LDS (xor-swizzle) with next-phase reg-prefetch. Epilogues
// emit SINGLE fp16 planes: Q row-major (scaled), K/V fragment-linear via
// one LDS scratch transpose. grid = (256 m-tiles, 4 col-tiles), 2 blocks/CU.
// ---------------------------------------------------------------------------
__global__ __launch_bounds__(256, 2) void qkv_proj(const float *__restrict__ X,
                                                   const __bf16 *__restrict__ Wht,
                                                   const __bf16 *__restrict__ Wlt,
                                                   _Float16 *__restrict__ Qf,
                                                   _Float16 *__restrict__ Kf,
                                                   _Float16 *__restrict__ Vf) {
  __shared__ __bf16 WhS[64 * 256];
  __shared__ __bf16 WlS[64 * 256];
  _Float16 *Tf = (_Float16 *)WhS;  // 64 x 72 fp16 scratch (aliases WhS)

  const int mtile = blockIdx.x;
  const int col0 = blockIdx.y * 64;
  const int tid = threadIdx.x;
  const int w4 = tid >> 6;
  const int lane = tid & 63;
  const int quad = lane >> 4;
  const int ln = lane & 15;
  const int arow = mtile * 64 + w4 * 16 + ln;

  bf16x8 ah[8], al[8];
  #pragma unroll
  for (int kc = 0; kc < 8; ++kc) {
    const float *xp = X + (size_t)arow * HID + kc * 32 + quad * 8;
    floatx4 x0 = *(const floatx4 *)xp;
    floatx4 x1 = *(const floatx4 *)(xp + 4);
    #pragma unroll
    for (int j = 0; j < 4; ++j) {
      __bf16 h, l;
      split_bf16(x0[j], h, l); ah[kc][j] = h; al[kc][j] = l;
      split_bf16(x1[j], h, l); ah[kc][4 + j] = h; al[kc][4 + j] = l;
    }
  }

  const int srow = tid >> 2;
  const int sseg = tid & 3;

  bf16x8 pwh[8], pwl[8];
  {
    const size_t wbase = (size_t)(col0 + srow) * HID;
    #pragma unroll
    for (int j = 0; j < 8; ++j) {
      const int chunk = j * 4 + sseg;
      pwh[j] = *(const bf16x8 *)&Wht[wbase + chunk * 8];
      pwl[j] = *(const bf16x8 *)&Wlt[wbase + chunk * 8];
    }
  }

  for (int w = 0; w < 3; ++w) {
    __syncthreads();  // W region free (prev MFMA reads / scratch reads done)
    #pragma unroll
    for (int j = 0; j < 8; ++j) {
      const int chunk = j * 4 + sseg;
      const int dst = srow * 256 + ((chunk ^ (srow & 7)) << 3);
      *(bf16x8 *)&WhS[dst] = pwh[j];
      *(bf16x8 *)&WlS[dst] = pwl[j];
    }
    __syncthreads();

    if (w < 2) {
      const size_t wbase = (size_t)(w + 1) * HID * HID + (size_t)(col0 + srow) * HID;
      #pragma unroll
      for (int j = 0; j < 8; ++j) {
        const int chunk = j * 4 + sseg;
        pwh[j] = *(const bf16x8 *)&Wht[wbase + chunk * 8];
        pwl[j] = *(const bf16x8 *)&Wlt[wbase + chunk * 8];
      }
    }

    floatx4 acc[4] = {};
    #pragma unroll
    for (int kc = 0; kc < 8; ++kc) {
      #pragma unroll
      for (int nt = 0; nt < 4; ++nt) {
        const int a = (nt * 16 + ln) * 256 + (((kc * 4 + quad) ^ (ln & 7)) << 3);
        bf16x8 bh = *(const bf16x8 *)&WhS[a];
        bf16x8 bl = *(const bf16x8 *)&WlS[a];
        acc[nt] = MFMA16B(ah[kc], bh, acc[nt]);
        acc[nt] = MFMA16B(ah[kc], bl, acc[nt]);
        acc[nt] = MFMA16B(al[kc], bh, acc[nt]);
      }
    }

    // Epilogues. C/D layout: col = lane&15, row = quad*4 + reg.
    if (w == 0) {
      #pragma unroll
      for (int nt = 0; nt < 4; ++nt) {
        #pragma unroll
        for (int r = 0; r < 4; ++r) {
          const int orow = mtile * 64 + w4 * 16 + quad * 4 + r;
          const int ocol = col0 + nt * 16 + ln;
          Qf[(size_t)orow * HID + ocol] = (_Float16)(acc[nt][r] * QSCALE);
        }
      }
    } else if (w == 1) {
      __syncthreads();  // all MFMA reads of WhS done before scratch clobber
      #pragma unroll
      for (int nt = 0; nt < 4; ++nt) {
        #pragma unroll
        for (int r = 0; r < 4; ++r) {
          const int tok_l = w4 * 16 + quad * 4 + r;
          const int h_l = nt * 16 + ln;
          Tf[tok_l * 72 + h_l] = (_Float16)acc[nt][r];
        }
      }
      __syncthreads();
      #pragma unroll
      for (int i = 0; i < 2; ++i) {     // 512 chunks of 16B
        const int c = i * 256 + tid;
        const int lane_f = c & 63;
        const int ntf = (c >> 6) & 1;
        const int kcL = (c >> 7) & 1;
        const int t2 = (c >> 8) & 1;
        const int qf = lane_f >> 4;
        const int lnf = lane_f & 15;
        const int tok_l = t2 * 32 + ntf * 16 + lnf;
        f16x8 v = *(const f16x8 *)&Tf[tok_l * 72 + kcL * 32 + qf * 8];
        const int T = mtile * 2 + t2;
        const int kc = (col0 >> 5) + kcL;
        *(f16x8 *)&Kf[(size_t)T * 8192 + ((ntf * 8 + kc) * 64 + lane_f) * 8] = v;
      }
    } else {
      __syncthreads();
      #pragma unroll
      for (int nt = 0; nt < 4; ++nt) {
        #pragma unroll
        for (int r = 0; r < 4; ++r) {
          const int tok_l = w4 * 16 + quad * 4 + r;
          const int d_l = nt * 16 + ln;
          Tf[d_l * 72 + tok_l] = (_Float16)acc[nt][r];
        }
      }
      __syncthreads();
      #pragma unroll
      for (int i = 0; i < 2; ++i) {     // 512 chunks of 16B
        const int c = i * 256 + tid;
        const int lane_f = c & 63;
        const int dtL = (c >> 6) & 3;
        const int t2 = (c >> 8) & 1;
        const int qf = lane_f >> 4;
        const int lnf = lane_f & 15;
        const int d_l = dtL * 16 + lnf;
        f16x8 v = *(const f16x8 *)&Tf[d_l * 72 + t2 * 32 + qf * 8];
        const int T = mtile * 2 + t2;
        const int dt = (col0 >> 4) + dtL;
        *(f16x8 *)&Vf[(size_t)(T * 16 + dt) * 512 + lane_f * 8] = v;
      }
    }
  }
}

// ---------------------------------------------------------------------------
// Kernel 3: flash attention, all-fp16 operands. grid = 1024 (qt=bx>>2,
// ks=bx&3), 256 thr. LDS 37888 B (KS0+KS1 32 KB + 5 KB P scratch) -> the
// HARDWARE allows 4 blocks/CU; launch_bounds stays (256,2) so the register
// allocator is NOT capped (r10 lesson: capping at 128 VGPR spilled the o[]
// accumulators -> 2.6 GB scratch traffic). Compiler uses ~112 VGPR -> 4
// waves/SIMD fits (448 <= 512) -> 4 resident blocks/CU without spills.
// Per 64-key macro: DMA-dbuf KS0/KS1 (16 KB tiles, one barrier each),
// single-product fp16 QK (2-way kc-split chains), ONE softmax, P round-trip
// in two 32-key halves through a reused per-wave scratch (DS pipe is
// in-order within a wave -> no barrier for the overwrite). V direct from
// global; DPP reductions; alpha-skip; setprio around MFMA clusters.
// ---------------------------------------------------------------------------
__global__ __launch_bounds__(256, 2) void attn(const _Float16 *__restrict__ Qf,
                                               const _Float16 *__restrict__ Kf,
                                               const _Float16 *__restrict__ Vf,
                                               _Float16 *__restrict__ Op,
                                               float *__restrict__ Mp,
                                               float *__restrict__ Lp) {
  __shared__ _Float16 KS0[8192];
  __shared__ _Float16 KS1[8192];
  __shared__ _Float16 PsS[4 * 16 * 40];  // per-wave 16 x 40 (32 keys + pad)

  const int bx = blockIdx.x;
  const int ks = bx & 3;
  const int qt = bx >> 2;
  const int b = qt >> 6;
  const int qtl = qt & 63;
  const int tid = threadIdx.x;
  const int w4 = tid >> 6;
  const int lane = tid & 63;
  const int quad = lane >> 4;
  const int ln = lane & 15;
  const int T0 = b * 128 + ks * 32;  // 32 key-tiles (1024 keys) per block

  const int qtok = b * LSEQ + qtl * 64 + w4 * 16 + ln;
  f16x8 q[8];
  #pragma unroll
  for (int kc = 0; kc < 8; ++kc)
    q[kc] = *(const f16x8 *)&Qf[(size_t)qtok * HID + kc * 32 + quad * 8];

  // Uniform bases (SALU) + fixed per-lane offsets.
  const _Float16 *kuni = Kf + (size_t)T0 * 8192;
  const _Float16 *vuni = Vf + (size_t)T0 * 8192;
  const int koff = tid * 8;
  const int voff = lane * 8;

  // Prologue: DMA tile 0 -> KS0 (4 rounds x 4 KB).
  #pragma unroll
  for (int i = 0; i < 4; ++i)
    GLOAD_LDS16(kuni + i * 2048 + koff, &KS0[i * 2048 + koff]);

  float m[4] = {-1e30f, -1e30f, -1e30f, -1e30f};
  float l[4] = {0.f, 0.f, 0.f, 0.f};
  floatx4 o[16] = {};

  for (int jm = 0; jm < 16; ++jm) {
    floatx4 s[4];
    // ---------- tile A (keys 64*jm..+31) from KS0 ----------
    __syncthreads();  // drains KS0's DMA; all waves done reading KS1 (prev macro)
    {
      const _Float16 *src = kuni + (size_t)(2 * jm + 1) * 8192 + koff;
      #pragma unroll
      for (int i = 0; i < 4; ++i)
        GLOAD_LDS16(src + i * 2048, &KS1[i * 2048 + koff]);
    }
    {
      floatx4 pa[2] = {}, pb[2] = {};
      __builtin_amdgcn_s_setprio(1);
      #pragma unroll
      for (int nt = 0; nt < 2; ++nt)
        #pragma unroll
        for (int kc = 0; kc < 4; ++kc) {
          pa[nt] = MFMA16F(q[kc], *(const f16x8 *)(KS0 + (nt * 8 + kc) * 512 + voff), pa[nt]);
          pb[nt] = MFMA16F(q[4 + kc], *(const f16x8 *)(KS0 + (nt * 8 + 4 + kc) * 512 + voff), pb[nt]);
        }
      __builtin_amdgcn_s_setprio(0);
      s[0] = pa[0] + pb[0];
      s[1] = pa[1] + pb[1];
    }
    // ---------- tile B (keys +32..+63) from KS1 ----------
    __syncthreads();  // drains KS1's DMA; all waves done reading KS0
    if (jm < 15) {
      const _Float16 *src = kuni + (size_t)(2 * jm + 2) * 8192 + koff;
      #pragma unroll
      for (int i = 0; i < 4; ++i)
        GLOAD_LDS16(src + i * 2048, &KS0[i * 2048 + koff]);
    }
    const _Float16 *va = vuni + (size_t)(2 * jm) * 8192;
    const _Float16 *vbp = vuni + (size_t)(2 * jm + 1) * 8192;
    f16x8 vb0[8];
    #pragma unroll
    for (int dt = 0; dt < 8; ++dt)
      vb0[dt] = *(const f16x8 *)(va + dt * 512 + voff);
    {
      floatx4 pa[2] = {}, pb[2] = {};
      __builtin_amdgcn_s_setprio(1);
      #pragma unroll
      for (int nt = 0; nt < 2; ++nt)
        #pragma unroll
        for (int kc = 0; kc < 4; ++kc) {
          pa[nt] = MFMA16F(q[kc], *(const f16x8 *)(KS1 + (nt * 8 + kc) * 512 + voff), pa[nt]);
          pb[nt] = MFMA16F(q[4 + kc], *(const f16x8 *)(KS1 + (nt * 8 + 4 + kc) * 512 + voff), pb[nt]);
        }
      __builtin_amdgcn_s_setprio(0);
      s[2] = pa[0] + pb[0];
      s[3] = pa[1] + pb[1];
    }
    f16x8 vb1[8];
    #pragma unroll
    for (int dt = 0; dt < 8; ++dt)
      vb1[dt] = *(const f16x8 *)(va + (8 + dt) * 512 + voff);

    // ---------- softmax over 64 keys (base-2, DPP) ----------
    float alpha[4];
    #pragma unroll
    for (int r = 0; r < 4; ++r) {
      const float tmax = row_max16(
          fmaxf(fmaxf(s[0][r], s[1][r]), fmaxf(s[2][r], s[3][r])));
      const float mn = fmaxf(m[r], tmax);
      const float al = exp2f(m[r] - mn);
      const float p0 = exp2f(s[0][r] - mn);
      const float p1 = exp2f(s[1][r] - mn);
      const float p2 = exp2f(s[2][r] - mn);
      const float p3 = exp2f(s[3][r] - mn);
      s[0][r] = p0; s[1][r] = p1; s[2][r] = p2; s[3][r] = p3;
      const float rs = row_sum16((p0 + p1) + (p2 + p3));
      l[r] = l[r] * al + rs;
      m[r] = mn;
      alpha[r] = al;
    }

    // ---------- P half A (keys 0..31) write: C-layout -> A-layout ----------
    _Float16 *ps = PsS + w4 * (16 * 40);
    #pragma unroll
    for (int nt = 0; nt < 2; ++nt)
      #pragma unroll
      for (int r = 0; r < 4; ++r)
        ps[(quad * 4 + r) * 40 + nt * 16 + ln] = (_Float16)s[nt][r];

    // ---------- O rescale (alpha-skip; near-one-hot -> mostly skipped) ------
    const float amin = fminf(fminf(alpha[0], alpha[1]), fminf(alpha[2], alpha[3]));
    if (__any(amin < 1.0f)) {
      #pragma unroll
      for (int dt = 0; dt < 16; ++dt) {
        o[dt][0] *= alpha[0]; o[dt][1] *= alpha[1];
        o[dt][2] *= alpha[2]; o[dt][3] *= alpha[3];
      }
    }

    const f16x8 paA = *(const f16x8 *)&ps[ln * 40 + quad * 8];

    // ---------- O += P V, keys 0..31 ----------
    __builtin_amdgcn_s_setprio(1);
    #pragma unroll
    for (int dt = 0; dt < 8; ++dt) o[dt] = MFMA16F(paA, vb0[dt], o[dt]);
    __builtin_amdgcn_s_setprio(0);
    f16x8 vb2[8];
    #pragma unroll
    for (int dt = 0; dt < 8; ++dt)
      vb2[dt] = *(const f16x8 *)(vbp + dt * 512 + voff);
    __builtin_amdgcn_s_setprio(1);
    #pragma unroll
    for (int dt = 0; dt < 8; ++dt) o[8 + dt] = MFMA16F(paA, vb1[dt], o[8 + dt]);
    __builtin_amdgcn_s_setprio(0);
    f16x8 vb3[8];
    #pragma unroll
    for (int dt = 0; dt < 8; ++dt)
      vb3[dt] = *(const f16x8 *)(vbp + (8 + dt) * 512 + voff);

    // ---------- P half B (keys 32..63): reuse scratch (DS in-order) --------
    #pragma unroll
    for (int nt = 0; nt < 2; ++nt)
      #pragma unroll
      for (int r = 0; r < 4; ++r)
        ps[(quad * 4 + r) * 40 + nt * 16 + ln] = (_Float16)s[2 + nt][r];

    const f16x8 paB = *(const f16x8 *)&ps[ln * 40 + quad * 8];

    // ---------- O += P V, keys 32..63 ----------
    __builtin_amdgcn_s_setprio(1);
    #pragma unroll
    for (int dt = 0; dt < 8; ++dt) o[dt] = MFMA16F(paB, vb2[dt], o[dt]);
    #pragma unroll
    for (int dt = 0; dt < 8; ++dt) o[8 + dt] = MFMA16F(paB, vb3[dt], o[8 + dt]);
    __builtin_amdgcn_s_setprio(0);
  }

  const int rowbase = b * LSEQ + qtl * 64 + w4 * 16 + quad * 4;
  #pragma unroll
  for (int dt = 0; dt < 16; ++dt)
    #pragma unroll
    for (int r = 0; r < 4; ++r)
      Op[(size_t)ks * PLANE + (size_t)(rowbase + r) * HID + dt * 16 + ln] =
          (_Float16)o[dt][r];
  if (ln == 0) {
    #pragma unroll
    for (int r = 0; r < 4; ++r) {
      Mp[ks * NTOK + rowbase + r] = m[r];
      Lp[ks * NTOK + rowbase + r] = l[r];
    }
  }
}

// ---------------------------------------------------------------------------
// Kernel 4: split-K merge, 4-way (fp16 partials).
// ---------------------------------------------------------------------------
__global__ __launch_bounds__(256) void merge(const _Float16 *__restrict__ Op,
                                             const float *__restrict__ Mp,
                                             const float *__restrict__ Lp,
                                             float *__restrict__ Out) {
  const int row = blockIdx.x * 4 + (threadIdx.x >> 6);
  const int c = (threadIdx.x & 63) * 4;
  float ms[NSPLIT], ls[NSPLIT];
  #pragma unroll
  for (int s = 0; s < NSPLIT; ++s) {
    ms[s] = Mp[s * NTOK + row];
    ls[s] = Lp[s * NTOK + row];
  }
  const float M = fmaxf(fmaxf(ms[0], ms[1]), fmaxf(ms[2], ms[3]));
  float e[NSPLIT], den = 0.f;
  #pragma unroll
  for (int s = 0; s < NSPLIT; ++s) {
    e[s] = exp2f(ms[s] - M);
    den += ls[s] * e[s];
  }
  const float inv = 1.0f / den;
  floatx4 out = {};
  #pragma unroll
  for (int s = 0; s < NSPLIT; ++s) {
    const f16x4 a = *(const f16x4 *)&Op[(size_t)s * PLANE + (size_t)row * HID + c];
    const float w = e[s] * inv;
    #pragma unroll
    for (int i = 0; i < 4; ++i) out[i] += w * (float)a[i];
  }
  *(floatx4 *)&Out[(size_t)row * HID + c] = out;
}

// ---------------------------------------------------------------------------
extern "C" void kernel_launch(void *const *d_in, const int *in_sizes, int n_in,
                              void *d_out, int out_size, void *d_ws, size_t ws_size,
                              hipStream_t stream) {
  const float *X = (const float *)d_in[0];
  const float *Wq = (const float *)d_in[1];
  const float *Wk = (const float *)d_in[2];
  const float *Wv = (const float *)d_in[3];
  // d_in[4] = lengths (unused by reference)

  // Workspace (2-byte elements). ~60 MB total.
  _Float16 *ws = (_Float16 *)d_ws;
  _Float16 *Qf = ws;                          // [16384][256] row-major fp16
  _Float16 *Kf = Qf + PLANE;                  // 32-key frag-linear fp16
  _Float16 *Vf = Kf + PLANE;                  // 32-key frag-linear fp16
  __bf16 *Wht = (__bf16 *)(Vf + PLANE);       // [3][256][256] bf16 hi
  __bf16 *Wlt = Wht + 3 * HID * HID;          // bf16 lo
  _Float16 *Op = (_Float16 *)(Wlt + 3 * HID * HID);  // [4][16384][256] fp16
  float *Mp = (float *)(Op + NSPLIT * PLANE); // [4][16384]
  float *Lp = Mp + NSPLIT * NTOK;             // [4][16384]

  wsplit<<<dim3(3, 8), 256, 0, stream>>>(Wq, Wk, Wv, Wht, Wlt);
  qkv_proj<<<dim3(256, 4), 256, 0, stream>>>(X, Wht, Wlt, Qf, Kf, Vf);
  attn<<<NTOK / 64 * NSPLIT, 256, 0, stream>>>(Qf, Kf, Vf, Op, Mp, Lp);
  merge<<<NTOK / 4, 256, 0, stream>>>(Op, Mp, Lp, (float *)d_out);
}